// Round 6
// baseline (3467.922 us; speedup 1.0000x reference)
//
#include <hip/hip_runtime.h>

#define S 128
#define NEGF (-1e30f)
#define MAXB 16
#define NT 512            // 8 waves per block

// Static device workspace (d_ws proved unreliable in rounds 0-2).
__device__ float g_ssg[MAXB * S * S];   // sibling spans, both orientations
__device__ float g_logZ[MAXB];
__device__ float g_partials[512];

__device__ __forceinline__ bool mask_at(const unsigned char* mask, int idx, bool bytes) {
  return bytes ? (mask[idx] != 0) : (((const int*)mask)[idx] != 0);
}

// global -> LDS DMA, 4B per lane: LDS dest = uniform base + lane*4,
// global src per-lane (m03/m97-verified gfx950 pattern).
__device__ __forceinline__ void gload_lds4(const float* g, float* l) {
  __builtin_amdgcn_global_load_lds(
      (const __attribute__((address_space(1))) unsigned int*)g,
      (__attribute__((address_space(3))) unsigned int*)l, 4, 0, 0);
}

// One block (512 threads) per batch element. One THREAD per lse task;
// reduction over split points is a serial two-pass (max, sum-exp) loop.
// State: si[head][dep], sc[head][end] in LDS; ssg (sibling spans) in global
// (L2-resident, same-block producer/consumer); sib rows for width w staged
// into LDS one width ahead via global_load_lds.
__global__ __launch_bounds__(NT) void dp_kernel(
    const float* __restrict__ arc,          // [B,S,S] s_arc[b,dep,head]
    const float* __restrict__ sib,          // [B,S,S,S] s_sib[b,dep,head,sib]
    const unsigned char* __restrict__ mask) // [B,S]
{
  __shared__ float si[S][S];
  __shared__ float sc[S][S];
  __shared__ float stage[7940];   // max 2*(nk-1)*(w-1) = 7938 floats
  __shared__ int len_sh, cnt0_sh;

  const int b = blockIdx.x;
  const int tid = threadIdx.x;
  const float* arc_b = arc + (size_t)b * S * S;      // arc_b[dep*S+head]
  const float* SBraw = sib + (size_t)b * S * S * S;  // SBraw[dep][head][sib]
  float* gss = g_ssg + (size_t)b * S * S;

  if (tid == 0) { len_sh = 0; cnt0_sh = 0; }
  __syncthreads();
  if (tid < S && mask[tid] != 0) atomicAdd(&cnt0_sh, 1);  // byte-interp of row 0
  for (int i = tid; i < S * S; i += NT) {
    (&si[0][0])[i] = NEGF;
    (&sc[0][0])[i] = NEGF;
  }
  __syncthreads();
  const bool bytes = (cnt0_sh >= 64);  // bool bytes: ~127 nonzero; int32: ~31
  if (tid < S) {
    sc[tid][tid] = 0.0f;
    if (mask_at(mask, b * S + tid, bytes)) atomicAdd(&len_sh, 1);
  }
  __syncthreads();
  const int len = min(len_sh, S - 1);
  if (tid == 0) g_logZ[b] = 0.0f;      // len==0 fallback

  // Pre-stage sib for w=... (w=1 has no sibling terms; first stage targets w=2
  // and is issued inside the w=1 iteration's phase-2 region below).

  for (int w = 1; w < S; ++w) {
    const int nk = S - w;

    // ================= phase 1: ir / il / slr (one thread per task) ========
    if (tid < 3 * nk) {
      int type, k;
      if (tid < nk)            { type = 0; k = tid; }
      else if (tid < 2 * nk)   { type = 1; k = tid - nk; }
      else                     { type = 2; k = tid - 2 * nk; }
      const int kw = k + w;
      if (type < 2) {
        float base, arcv;
        const float* srow;
        const float* grow;
        if (type == 0) {       // I(k -> kw): base j=0, siblings x in (k, kw)
          base = sc[k][k] + sc[kw][k + 1];
          arcv = arc_b[kw * S + k];
          srow = &si[k][0];
          grow = gss + kw * S;
        } else {               // I(kw -> k): base j=w-1, siblings x in (k, k+w)
          base = (k == 0) ? 0.0f : (sc[kw][kw] + sc[k][kw - 1]);
          arcv = arc_b[k * S + kw];
          srow = &si[kw][0];
          grow = gss + k * S;
        }
        float m = base, ssum;
        if (k >= 1 && w >= 2) {
          const float* strow = &stage[(type * (nk - 1) + (k - 1)) * (w - 1)] - (k + 1);
#pragma unroll 8
          for (int x = k + 1; x < kw; ++x)
            m = fmaxf(m, srow[x] + grow[x] + strow[x]);
          ssum = __expf(base - m);
#pragma unroll 8
          for (int x = k + 1; x < kw; ++x)
            ssum += __expf(srow[x] + grow[x] + strow[x] - m);
        } else ssum = 1.0f;
        const float r = __logf(ssum) + m + arcv;
        if (type == 0) si[k][kw] = r;
        else           si[kw][k] = r;
      } else if (k >= 1) {     // S(k,kw) = lse_x sc[k][x] + sc[kw][x+1]
        const float* ra = &sc[k][0];
        const float* rb = &sc[kw][0];
        float m = NEGF, ssum = 0.f;
#pragma unroll 8
        for (int x = k; x < kw; ++x) m = fmaxf(m, ra[x] + rb[x + 1]);
#pragma unroll 8
        for (int x = k; x < kw; ++x) ssum += __expf(ra[x] + rb[x + 1] - m);
        const float r = __logf(ssum) + m;
        gss[k * S + kw] = r;
        gss[kw * S + k] = r;
      }
    }
    __syncthreads();

    // ======== stage sib rows for width w+1 (DMA; drains at next barrier) ====
    const int wn = w + 1;
    if (wn < S) {
      const int nk2 = S - wn;
      const int R = 2 * (nk2 - 1);      // rows: k in [1,nk2) x {type0,type1}
      const int rowlen = wn - 1;        // = w
      const int l = tid & 63;
      for (int r = (tid >> 6); r < R; r += 8) {   // wave-uniform row loop
        const int buf = r & 1;
        const int k = 1 + (r >> 1);
        const int kw2 = k + wn;
        const size_t srcoff = (buf == 0)
            ? ((size_t)(kw2 * S + k) * S + (k + 1))    // type0: sib[dep=kw][head=k][k+1..]
            : ((size_t)(k * S + kw2) * S + (k + 1));   // type1: sib[dep=k][head=kw][k+1..]
        const float* src = SBraw + srcoff;
        float* dst = &stage[(buf * (nk2 - 1) + (k - 1)) * rowlen];
        if (l < rowlen) gload_lds4(src + l, dst);
        if (rowlen > 64 && l < rowlen - 64) gload_lds4(src + 64 + l, dst + 64);
      }
    }

    // ================= phase 2: cl / cr (one thread per task) ===============
    if (tid < 2 * nk) {
      const bool is_cl = tid < nk;
      const int k = is_cl ? tid : tid - nk;
      const int kw = k + w;
      float m = NEGF, ssum = 0.f;
      if (is_cl) {             // C(kw -> k) = lse_x sc[x][k] + si[kw][x]
        const float* srow = &si[kw][0];
#pragma unroll 8
        for (int x = k; x < kw; ++x) m = fmaxf(m, sc[x][k] + srow[x]);
#pragma unroll 8
        for (int x = k; x < kw; ++x) ssum += __expf(sc[x][k] + srow[x] - m);
        sc[kw][k] = __logf(ssum) + m;
      } else {                 // C(k -> kw) = lse_y si[k][y] + sc[y][kw]
        const float* srow = &si[k][0];
#pragma unroll 8
        for (int y = k + 1; y <= kw; ++y) m = fmaxf(m, srow[y] + sc[y][kw]);
#pragma unroll 8
        for (int y = k + 1; y <= kw; ++y) ssum += __expf(srow[y] + sc[y][kw] - m);
        const float r = __logf(ssum) + m;
        if (k == 0) {
          // single-root kill: C(0->w) survives only at w == len
          if (w == len) g_logZ[b] = r;
          sc[0][w] = (w == len) ? r : NEGF;
        } else {
          sc[k][kw] = r;
        }
      }
    }
    __syncthreads();
  }
}

// Gather score: masked arc scores + positive-sibling scores, count mask.
__global__ __launch_bounds__(256) void score_kernel(
    const float* __restrict__ arc, const float* __restrict__ sib,
    const unsigned char* __restrict__ mask, const int* __restrict__ arcs,
    const int* __restrict__ sibs, int B)
{
  __shared__ bool bytes_sh;
  if (threadIdx.x == 0) {
    int c = 0;
    for (int i = 0; i < S; ++i) c += (mask[i] != 0);
    bytes_sh = (c >= 64);
  }
  __syncthreads();
  const bool bytes = bytes_sh;

  const int total = B * S * S;
  int tid = blockIdx.x * blockDim.x + threadIdx.x;
  float sum = 0.f, cnt = 0.f;
  for (int e = tid; e < total; e += gridDim.x * blockDim.x) {
    int sv = sibs[e];
    if (sv > 0) sum += sib[(size_t)e * S + sv];
    if ((e & (S - 1)) == 0) {           // once per (b,i)
      int bi = e >> 7;
      if (mask_at(mask, bi, bytes)) { sum += arc[(size_t)bi * S + arcs[bi]]; cnt += 1.f; }
    }
  }
  __shared__ float rs[256], rc[256];
  rs[threadIdx.x] = sum; rc[threadIdx.x] = cnt;
  __syncthreads();
  for (int off = 128; off; off >>= 1) {
    if (threadIdx.x < off) {
      rs[threadIdx.x] += rs[threadIdx.x + off];
      rc[threadIdx.x] += rc[threadIdx.x + off];
    }
    __syncthreads();
  }
  if (threadIdx.x == 0) {
    g_partials[blockIdx.x * 2]     = rs[0];
    g_partials[blockIdx.x * 2 + 1] = rc[0];
  }
}

__global__ __launch_bounds__(256) void final_kernel(int B, float* __restrict__ out)
{
  __shared__ float rs[256], rc[256];
  int t = threadIdx.x;
  float v = -g_partials[t * 2];
  float c = g_partials[t * 2 + 1];
  if (t < B) v += g_logZ[t];
  rs[t] = v; rc[t] = c;
  __syncthreads();
  for (int off = 128; off; off >>= 1) {
    if (t < off) { rs[t] += rs[t + off]; rc[t] += rc[t + off]; }
    __syncthreads();
  }
  if (t == 0) out[0] = rs[0] / rc[0];   // (logZ - score) / mask.sum()
}

extern "C" void kernel_launch(void* const* d_in, const int* in_sizes, int n_in,
                              void* d_out, int out_size, void* d_ws, size_t ws_size,
                              hipStream_t stream) {
  const float* s_arc = (const float*)d_in[0];
  const float* s_sib = (const float*)d_in[1];
  const unsigned char* mask = (const unsigned char*)d_in[2];
  const int* arcs = (const int*)d_in[3];
  const int* sibs = (const int*)d_in[4];
  int B = in_sizes[0] / (S * S);
  if (B > MAXB) B = MAXB;

  score_kernel<<<dim3(256), dim3(256), 0, stream>>>(s_arc, s_sib, mask, arcs, sibs, B);
  dp_kernel<<<dim3(B), dim3(NT), 0, stream>>>(s_arc, s_sib, mask);
  final_kernel<<<dim3(1), dim3(256), 0, stream>>>(B, (float*)d_out);
}

// Round 7
// 981.247 us; speedup vs baseline: 3.5342x; 3.5342x over previous
//
#include <hip/hip_runtime.h>

#define S 128
#define NEGF (-1e30f)
#define MAXB 16
#define NT 512
#define SIP 129   // si row stride (pad: diagonal reads land on distinct banks mod-32 pairs)

// Static device workspace (d_ws proved unreliable in rounds 0-2).
__device__ float g_ssw[MAXB * S * S];   // sibling spans, [b][width][start] layout
__device__ float g_logZ[MAXB];
__device__ float g_partials[512];

__device__ __forceinline__ bool mask_at(const unsigned char* m, int i, bool by) {
  return by ? (m[i] != 0) : (((const int*)m)[i] != 0);
}

// global -> LDS DMA, 4B/lane: LDS dest = uniform base + lane*4 (r6-verified).
__device__ __forceinline__ void gload_lds4(const float* g, float* l) {
  __builtin_amdgcn_global_load_lds(
      (const __attribute__((address_space(1))) unsigned int*)g,
      (__attribute__((address_space(3))) unsigned int*)l, 4, 0, 0);
}

// Online-lse update. Finite NEGF sentinel: NEGF-NEGF=0 (no NaN), exp(NEGF-x)=0.
__device__ __forceinline__ void upd(float& m, float& s, float v) {
  float mn = fmaxf(m, v);
  s = s * __expf(m - mn) + __expf(v - mn);
  m = mn;
}
__device__ __forceinline__ float fin4(float m0, float s0, float m1, float s1,
                                      float m2, float s2, float m3, float s3) {
  float m = fmaxf(fmaxf(m0, m1), fmaxf(m2, m3));
  float s = s0 * __expf(m0 - m) + s1 * __expf(m1 - m) +
            s2 * __expf(m2 - m) + s3 * __expf(m3 - m);
  return __logf(s) + m;
}

// One block (512 thr) per batch element; one THREAD per lse task (lane=k),
// serial over split offset d. All per-iteration accesses are lane-consecutive:
//   si[.][k+d] diag (LDS, padded), sc[x][k] cols (LDS, bank=k), SSW[r][k+d]
//   (global L2, coalesced), stage sib rows (LDS, DMA-staged one width ahead).
__global__ __launch_bounds__(NT) void dp_kernel(
    const float* __restrict__ arc,          // [B,S,S] s_arc[b,dep,head]
    const float* __restrict__ sib,          // [B,S,S,S] s_sib[b,dep,head,sib]
    const unsigned char* __restrict__ mask) // [B,S]
{
  __shared__ float si[S][SIP];
  __shared__ float sc[S][S];
  __shared__ float stage[7938];   // max 2*(nk-1)*(w-1) floats (w=64)
  __shared__ int len_sh, cnt0_sh;

  const int b = blockIdx.x;
  const int tid = threadIdx.x;
  const float* arc_b = arc + (size_t)b * S * S;      // arc_b[dep*S+head]
  const float* SBraw = sib + (size_t)b * S * S * S;  // SBraw[dep][head][sib]
  float* ssw = g_ssw + (size_t)b * S * S;

  if (tid == 0) { len_sh = 0; cnt0_sh = 0; }
  __syncthreads();
  if (tid < S && mask[tid] != 0) atomicAdd(&cnt0_sh, 1);  // byte-interp of row 0
  for (int i = tid; i < S * SIP; i += NT) (&si[0][0])[i] = NEGF;
  for (int i = tid; i < S * S; i += NT) (&sc[0][0])[i] = NEGF;
  __syncthreads();
  const bool bytes = (cnt0_sh >= 64);  // bool bytes: ~127 nonzero; int32: ~31
  if (tid < S) {
    sc[tid][tid] = 0.0f;               // width-0 complete spans
    if (mask_at(mask, b * S + tid, bytes)) atomicAdd(&len_sh, 1);
  }
  __syncthreads();
  const int len = min(len_sh, S - 1);
  if (tid == 0) g_logZ[b] = 0.0f;      // len==0 fallback

  const int seg = tid >> 7;   // phase1: 0=ir, 1=il, 2=slr, 3=idle
  const int kk = tid & 127;

  for (int w = 1; w < S; ++w) {
    const int nk = S - w;
    const int n1 = w - 1;

    // ================= phase 1: ir / il / slr =================
    if (seg < 2 && kk < nk) {
      const int k = kk, kw = k + w;
      float bm, arcv;
      const float *pa, *pt, *pw_;
      int wstr;
      if (seg == 0) {           // ir: I(k -> kw), siblings x=k+1..kw-1
        bm = sc[k][k] + sc[kw][k + 1];
        arcv = arc_b[kw * S + k];
        pa = &si[k][k + 1];
        pt = &stage[(k >= 1 ? k - 1 : 0) * n1];
        pw_ = ssw + (w - 1) * S + (k + 1);  // SSW[w-1-i][k+1+i] = span(x,kw)
        wstr = 1 - S;
      } else {                  // il: I(kw -> k), siblings x=k+1..kw-1
        bm = (k == 0) ? 0.0f : (sc[kw][kw] + sc[k][kw - 1]);
        arcv = arc_b[k * S + kw];
        pa = &si[kw][k + 1];
        pt = &stage[((nk - 1) + (k >= 1 ? k - 1 : 0)) * n1];
        pw_ = ssw + S + k;                  // SSW[1+i][k] = span(k,x)
        wstr = S;
      }
      float m0 = bm, s0 = 1.f, m1 = NEGF, s1 = 0.f,
            m2 = NEGF, s2 = 0.f, m3 = NEGF, s3 = 0.f;
      if (k >= 1) {
        int i = 0;
#pragma unroll 2
        for (; i + 4 <= n1; i += 4) {
          float v0 = pa[i]     + pt[i]     + pw_[i * wstr];
          float v1 = pa[i + 1] + pt[i + 1] + pw_[(i + 1) * wstr];
          float v2 = pa[i + 2] + pt[i + 2] + pw_[(i + 2) * wstr];
          float v3 = pa[i + 3] + pt[i + 3] + pw_[(i + 3) * wstr];
          upd(m0, s0, v0); upd(m1, s1, v1); upd(m2, s2, v2); upd(m3, s3, v3);
        }
        for (; i < n1; ++i) upd(m0, s0, pa[i] + pt[i] + pw_[i * wstr]);
      }
      float r = fin4(m0, s0, m1, s1, m2, s2, m3, s3) + arcv;
      if (seg == 0) si[k][kw] = r;
      else          si[kw][k] = r;
    } else if (seg == 2 && kk >= 1 && kk < nk) {   // slr: S(k,kw)
      const int k = kk, kw = k + w;
      const float* ra = &sc[k][k];        // C(k -> k+i)
      const float* rb = &sc[kw][k + 1];   // C(kw -> k+i+1)
      float m0 = NEGF, s0 = 0.f, m1 = NEGF, s1 = 0.f,
            m2 = NEGF, s2 = 0.f, m3 = NEGF, s3 = 0.f;
      int i = 0;
#pragma unroll 2
      for (; i + 4 <= w; i += 4) {
        upd(m0, s0, ra[i]     + rb[i]);
        upd(m1, s1, ra[i + 1] + rb[i + 1]);
        upd(m2, s2, ra[i + 2] + rb[i + 2]);
        upd(m3, s3, ra[i + 3] + rb[i + 3]);
      }
      for (; i < w; ++i) upd(m0, s0, ra[i] + rb[i]);
      ssw[w * S + k] = fin4(m0, s0, m1, s1, m2, s2, m3, s3);
    }
    __syncthreads();

    // ========== DMA sib stage for width w+1 (drains at next barrier) ========
    const int wn = w + 1;
    if (wn < S) {
      const int nk2 = S - wn;
      const int R = 2 * (nk2 - 1);
      const int rowlen = wn - 1;
      const int l = tid & 63;
      for (int r = (tid >> 6); r < R; r += 8) {
        const int buf = r & 1;
        const int k = 1 + (r >> 1);
        const int kw2 = k + wn;
        const size_t srcoff = (buf == 0)
            ? ((size_t)(kw2 * S + k) * S + (k + 1))   // ir: sib[dep=kw][head=k][x]
            : ((size_t)(k * S + kw2) * S + (k + 1));  // il: sib[dep=k][head=kw][x]
        const float* src = SBraw + srcoff;
        float* dst = &stage[(buf * (nk2 - 1) + (k - 1)) * rowlen];
        if (l < rowlen) gload_lds4(src + l, dst);
        if (rowlen > 64 && l < rowlen - 64) gload_lds4(src + 64 + l, dst + 64);
      }
    }

    // ================= phase 2: cl / cr =================
    if (seg < 2 && kk < nk) {
      const int k = kk, kw = k + w;
      float m0 = NEGF, s0 = 0.f, m1 = NEGF, s1 = 0.f,
            m2 = NEGF, s2 = 0.f, m3 = NEGF, s3 = 0.f;
      if (seg == 0) {           // cl: C(kw->k) over x=k..kw-1: sc[x][k]+si[kw][x]
        const float* pA = &sc[k][k];      // pA[i*S] = sc[k+i][k]  (bank = k)
        const float* pB = &si[kw][k];
        int i = 0;
#pragma unroll 2
        for (; i + 4 <= w; i += 4) {
          upd(m0, s0, pA[i * S]       + pB[i]);
          upd(m1, s1, pA[(i + 1) * S] + pB[i + 1]);
          upd(m2, s2, pA[(i + 2) * S] + pB[i + 2]);
          upd(m3, s3, pA[(i + 3) * S] + pB[i + 3]);
        }
        for (; i < w; ++i) upd(m0, s0, pA[i * S] + pB[i]);
        sc[kw][k] = fin4(m0, s0, m1, s1, m2, s2, m3, s3);
      } else {                  // cr: C(k->kw) over y=k+1..kw: si[k][y]+sc[y][kw]
        const float* pA = &si[k][k + 1];
        const float* pB = &sc[k + 1][kw]; // pB[i*S] = sc[k+1+i][kw]
        int i = 0;
#pragma unroll 2
        for (; i + 4 <= w; i += 4) {
          upd(m0, s0, pA[i]     + pB[i * S]);
          upd(m1, s1, pA[i + 1] + pB[(i + 1) * S]);
          upd(m2, s2, pA[i + 2] + pB[(i + 2) * S]);
          upd(m3, s3, pA[i + 3] + pB[(i + 3) * S]);
        }
        for (; i < w; ++i) upd(m0, s0, pA[i] + pB[i * S]);
        const float r = fin4(m0, s0, m1, s1, m2, s2, m3, s3);
        if (k == 0) {
          // single-root kill: C(0->w) survives only at w == len
          if (w == len) g_logZ[b] = r;
          sc[0][w] = (w == len) ? r : NEGF;
        } else {
          sc[k][kw] = r;
        }
      }
    }
    __syncthreads();
  }
}

// Gather score: masked arc scores + positive-sibling scores, count mask.
__global__ __launch_bounds__(256) void score_kernel(
    const float* __restrict__ arc, const float* __restrict__ sib,
    const unsigned char* __restrict__ mask, const int* __restrict__ arcs,
    const int* __restrict__ sibs, int B)
{
  __shared__ bool bytes_sh;
  if (threadIdx.x == 0) {
    int c = 0;
    for (int i = 0; i < S; ++i) c += (mask[i] != 0);
    bytes_sh = (c >= 64);
  }
  __syncthreads();
  const bool bytes = bytes_sh;

  const int total = B * S * S;
  int tid = blockIdx.x * blockDim.x + threadIdx.x;
  float sum = 0.f, cnt = 0.f;
  for (int e = tid; e < total; e += gridDim.x * blockDim.x) {
    int sv = sibs[e];
    if (sv > 0) sum += sib[(size_t)e * S + sv];
    if ((e & (S - 1)) == 0) {           // once per (b,i)
      int bi = e >> 7;
      if (mask_at(mask, bi, bytes)) { sum += arc[(size_t)bi * S + arcs[bi]]; cnt += 1.f; }
    }
  }
  __shared__ float rs[256], rc[256];
  rs[threadIdx.x] = sum; rc[threadIdx.x] = cnt;
  __syncthreads();
  for (int off = 128; off; off >>= 1) {
    if (threadIdx.x < off) {
      rs[threadIdx.x] += rs[threadIdx.x + off];
      rc[threadIdx.x] += rc[threadIdx.x + off];
    }
    __syncthreads();
  }
  if (threadIdx.x == 0) {
    g_partials[blockIdx.x * 2]     = rs[0];
    g_partials[blockIdx.x * 2 + 1] = rc[0];
  }
}

__global__ __launch_bounds__(256) void final_kernel(int B, float* __restrict__ out)
{
  __shared__ float rs[256], rc[256];
  int t = threadIdx.x;
  float v = -g_partials[t * 2];
  float c = g_partials[t * 2 + 1];
  if (t < B) v += g_logZ[t];
  rs[t] = v; rc[t] = c;
  __syncthreads();
  for (int off = 128; off; off >>= 1) {
    if (t < off) { rs[t] += rs[t + off]; rc[t] += rc[t + off]; }
    __syncthreads();
  }
  if (t == 0) out[0] = rs[0] / rc[0];   // (logZ - score) / mask.sum()
}

extern "C" void kernel_launch(void* const* d_in, const int* in_sizes, int n_in,
                              void* d_out, int out_size, void* d_ws, size_t ws_size,
                              hipStream_t stream) {
  const float* s_arc = (const float*)d_in[0];
  const float* s_sib = (const float*)d_in[1];
  const unsigned char* mask = (const unsigned char*)d_in[2];
  const int* arcs = (const int*)d_in[3];
  const int* sibs = (const int*)d_in[4];
  int B = in_sizes[0] / (S * S);
  if (B > MAXB) B = MAXB;

  score_kernel<<<dim3(256), dim3(256), 0, stream>>>(s_arc, s_sib, mask, arcs, sibs, B);
  dp_kernel<<<dim3(B), dim3(NT), 0, stream>>>(s_arc, s_sib, mask);
  final_kernel<<<dim3(1), dim3(256), 0, stream>>>(B, (float*)d_out);
}

// Round 8
// 877.377 us; speedup vs baseline: 3.9526x; 1.1184x over previous
//
#include <hip/hip_runtime.h>

#define S 128
#define NEGF (-1e30f)
#define MAXB 16
#define NT 512
#define STAGE_SZ 8064   // max over w of 2*(nk-1)*((w-1)|1), at wn=63

// Static device workspace (d_ws proved unreliable in rounds 0-2).
__device__ float g_ssw[MAXB * S * S];   // sibling spans, [b][width][start]
__device__ float g_logZ[MAXB];
__device__ float g_partials[512];

__device__ __forceinline__ bool mask_at(const unsigned char* m, int i, bool by) {
  return by ? (m[i] != 0) : (((const int*)m)[i] != 0);
}

// global -> LDS DMA, 4B/lane: LDS dest = uniform base + lane*4 (r6-verified).
__device__ __forceinline__ void gload_lds4(const float* g, float* l) {
  __builtin_amdgcn_global_load_lds(
      (const __attribute__((address_space(1))) unsigned int*)g,
      (__attribute__((address_space(3))) unsigned int*)l, 4, 0, 0);
}

// Online-lse pieces. Finite NEGF sentinel: no inf => no NaN with fast math.
__device__ __forceinline__ void upd(float& m, float& s, float v) {
  float mn = fmaxf(m, v);
  s = s * __expf(m - mn) + __expf(v - mn);
  m = mn;
}
__device__ __forceinline__ void fold(float& m0, float& s0, float m1, float s1) {
  float mn = fmaxf(m0, m1);
  s0 = s0 * __expf(m0 - mn) + s1 * __expf(m1 - mn);
  m0 = mn;
}
template <int CTRL>
__device__ __forceinline__ float dpp_f(float x) {
  int i = __float_as_int(x);
  return __int_as_float(__builtin_amdgcn_update_dpp(i, i, CTRL, 0xF, 0xF, false));
}
// Cross-lane combine of (m,s) over p=2^lp2 adjacent lanes (same wave, DPP),
// then finish log. Valid result on every lane of the group; writer is q==0.
__device__ __forceinline__ float xfinish(float m, float s, int lp2) {
  if (lp2 >= 1) { float mo = dpp_f<0xB1>(m), so = dpp_f<0xB1>(s); fold(m, s, mo, so); }
  if (lp2 >= 2) { float mo = dpp_f<0x4E>(m), so = dpp_f<0x4E>(s); fold(m, s, mo, so); }
  return __logf(s) + m;
}

// One block (512 thr) per batch element; lane=task, serial over split offset.
// Phase-1 inner loops are pure-LDS (sib+SSW pre-combined into stage by the
// enrich phase); width-adaptive p-way lane-split shortens serial loops at
// large w. States: si/sc in LDS, SSW in global (L2), sib DMA-staged.
__global__ __launch_bounds__(NT) void dp_kernel(
    const float* __restrict__ arc,          // [B,S,S] s_arc[b,dep,head]
    const float* __restrict__ sib,          // [B,S,S,S] s_sib[b,dep,head,sib]
    const unsigned char* __restrict__ mask) // [B,S]
{
  __shared__ float si[S][S];
  __shared__ float sc[S][S];
  __shared__ float stage[STAGE_SZ];
  __shared__ int len_sh, cnt0_sh;

  const int b = blockIdx.x;
  const int tid = threadIdx.x;
  const float* arc_b = arc + (size_t)b * S * S;      // arc_b[dep*S+head]
  const float* SBraw = sib + (size_t)b * S * S * S;  // SBraw[dep][head][sib]
  float* ssw = g_ssw + (size_t)b * S * S;

  if (tid == 0) { len_sh = 0; cnt0_sh = 0; }
  __syncthreads();
  if (tid < S && mask[tid] != 0) atomicAdd(&cnt0_sh, 1);  // byte-interp of row 0
  for (int i = tid; i < S * S; i += NT) {
    (&si[0][0])[i] = NEGF;
    (&sc[0][0])[i] = NEGF;
  }
  __syncthreads();
  const bool bytes = (cnt0_sh >= 64);  // bool bytes: ~127 nonzero; int32: ~31
  if (tid < S) {
    sc[tid][tid] = 0.0f;               // width-0 complete spans
    if (mask_at(mask, b * S + tid, bytes)) atomicAdd(&len_sh, 1);
  }
  __syncthreads();
  const int len = min(len_sh, S - 1);
  if (tid == 0) g_logZ[b] = 0.0f;      // len==0 fallback

  const int seg = tid >> 7;   // 0,1: ir/il (ph1) or cl/cr (ph2); 2: slr; 3: idle
  const int kkk = tid & 127;

  for (int w = 1; w < S; ++w) {
    const int nk = S - w;
    const int n1 = w - 1;
    const int rlP = n1 | 1;                      // stage row stride (odd)
    const int lp2 = (nk <= 32) ? 2 : ((nk <= 64) ? 1 : 0);
    const int p = 1 << lp2;
    const int q = kkk & (p - 1);
    const int k = kkk >> lp2;

    // ================= phase 1: ir / il / slr =================
    if (seg < 2 && k < nk) {
      const int kw = k + w;
      float bm, arcv;
      const float *pa, *pt;
      if (seg == 0) {          // ir: I(k -> kw), siblings x=k+1..kw-1
        bm = sc[k][k] + sc[kw][k + 1];
        arcv = arc_b[kw * S + k];
        pa = &si[k][k + 1];
        pt = &stage[(k >= 1 ? k - 1 : 0) * rlP];
      } else {                 // il: I(kw -> k), siblings x=k+1..kw-1
        bm = (k == 0) ? 0.0f : (sc[kw][kw] + sc[k][kw - 1]);
        arcv = arc_b[k * S + kw];
        pa = &si[kw][k + 1];
        pt = &stage[((nk - 1) + (k >= 1 ? k - 1 : 0)) * rlP];
      }
      float m0 = (q == 0) ? bm : NEGF, s0 = (q == 0) ? 1.f : 0.f;
      float m1 = NEGF, s1 = 0.f, m2 = NEGF, s2 = 0.f, m3 = NEGF, s3 = 0.f;
      if (k >= 1 && n1 > 0) {
        const int ch = n1 >> lp2;
        int i = q * ch;
        const int ie = (q == p - 1) ? n1 : i + ch;
#pragma unroll 2
        for (; i + 4 <= ie; i += 4) {
          upd(m0, s0, pa[i]     + pt[i]);
          upd(m1, s1, pa[i + 1] + pt[i + 1]);
          upd(m2, s2, pa[i + 2] + pt[i + 2]);
          upd(m3, s3, pa[i + 3] + pt[i + 3]);
        }
        for (; i < ie; ++i) upd(m0, s0, pa[i] + pt[i]);
      }
      fold(m0, s0, m1, s1); fold(m2, s2, m3, s3); fold(m0, s0, m2, s2);
      const float r = xfinish(m0, s0, lp2) + arcv;
      if (q == 0) {
        if (seg == 0) si[k][kw] = r;
        else          si[kw][k] = r;
      }
    } else if (seg == 2 && k >= 1 && k < nk) {   // slr: S(k,kw)
      const int kw = k + w;
      const float* ra = &sc[k][k];        // C(k -> k+i)
      const float* rb = &sc[kw][k + 1];   // C(kw -> k+i+1)
      float m0 = NEGF, s0 = 0.f, m1 = NEGF, s1 = 0.f,
            m2 = NEGF, s2 = 0.f, m3 = NEGF, s3 = 0.f;
      const int ch = w >> lp2;
      int i = q * ch;
      const int ie = (q == p - 1) ? w : i + ch;
#pragma unroll 2
      for (; i + 4 <= ie; i += 4) {
        upd(m0, s0, ra[i]     + rb[i]);
        upd(m1, s1, ra[i + 1] + rb[i + 1]);
        upd(m2, s2, ra[i + 2] + rb[i + 2]);
        upd(m3, s3, ra[i + 3] + rb[i + 3]);
      }
      for (; i < ie; ++i) upd(m0, s0, ra[i] + rb[i]);
      fold(m0, s0, m1, s1); fold(m2, s2, m3, s3); fold(m0, s0, m2, s2);
      const float r = xfinish(m0, s0, lp2);
      if (q == 0) ssw[w * S + k] = r;
    }
    __syncthreads();   // B1: si/ssw(w) final; stage(w) dead

    // ========== DMA sib stage for width w+1 (drains at B2) ==========
    const int wn = w + 1;
    if (wn < S) {
      const int nk2 = S - wn;
      const int R = 2 * (nk2 - 1);
      const int rowlen = wn - 1;
      const int rlP2 = rowlen | 1;
      const int l = tid & 63;
      for (int r = (tid >> 6); r < R; r += 8) {
        const int buf = r & 1;
        const int kr = 1 + (r >> 1);
        const int kw2 = kr + wn;
        const size_t srcoff = (buf == 0)
            ? ((size_t)(kw2 * S + kr) * S + (kr + 1))   // ir: sib[dep=kw][head=k][x]
            : ((size_t)(kr * S + kw2) * S + (kr + 1));  // il: sib[dep=k][head=kw][x]
        const float* src = SBraw + srcoff;
        float* dst = &stage[(buf * (nk2 - 1) + (kr - 1)) * rlP2];
        if (l < rowlen) gload_lds4(src + l, dst);
        if (rowlen > 64 && l < rowlen - 64) gload_lds4(src + 64 + l, dst + 64);
      }
    }

    // ================= phase 2: cl / cr =================
    if (seg < 2 && k < nk) {
      const int kw = k + w;
      float m0 = NEGF, s0 = 0.f, m1 = NEGF, s1 = 0.f,
            m2 = NEGF, s2 = 0.f, m3 = NEGF, s3 = 0.f;
      const int ch = w >> lp2;
      int i = q * ch;
      const int ie = (q == p - 1) ? w : i + ch;
      if (seg == 0) {          // cl: C(kw->k) over x=k..kw-1: sc[x][k]+si[kw][x]
        const float* pA = &sc[k][k];      // pA[i*S] = sc[k+i][k]
        const float* pB = &si[kw][k];
#pragma unroll 2
        for (; i + 4 <= ie; i += 4) {
          upd(m0, s0, pA[i * S]       + pB[i]);
          upd(m1, s1, pA[(i + 1) * S] + pB[i + 1]);
          upd(m2, s2, pA[(i + 2) * S] + pB[i + 2]);
          upd(m3, s3, pA[(i + 3) * S] + pB[i + 3]);
        }
        for (; i < ie; ++i) upd(m0, s0, pA[i * S] + pB[i]);
        fold(m0, s0, m1, s1); fold(m2, s2, m3, s3); fold(m0, s0, m2, s2);
        const float r = xfinish(m0, s0, lp2);
        if (q == 0) sc[kw][k] = r;
      } else {                 // cr: C(k->kw) over y=k+1..kw: si[k][y]+sc[y][kw]
        const float* pA = &si[k][k + 1];
        const float* pB = &sc[k + 1][kw]; // pB[i*S] = sc[k+1+i][kw]
#pragma unroll 2
        for (; i + 4 <= ie; i += 4) {
          upd(m0, s0, pA[i]     + pB[i * S]);
          upd(m1, s1, pA[i + 1] + pB[(i + 1) * S]);
          upd(m2, s2, pA[i + 2] + pB[(i + 2) * S]);
          upd(m3, s3, pA[i + 3] + pB[(i + 3) * S]);
        }
        for (; i < ie; ++i) upd(m0, s0, pA[i] + pB[i * S]);
        fold(m0, s0, m1, s1); fold(m2, s2, m3, s3); fold(m0, s0, m2, s2);
        const float r = xfinish(m0, s0, lp2);
        if (q == 0) {
          if (k == 0) {
            // single-root kill: C(0->w) survives only at w == len
            if (w == len) g_logZ[b] = r;
            sc[0][w] = (w == len) ? r : NEGF;
          } else {
            sc[k][kw] = r;
          }
        }
      }
    }
    __syncthreads();   // B2: sc(w) final; DMA(w+1) landed

    // ==== enrich: stage(w+1) += SSW terms (coalesced L2 reads, parallel) ====
    if (wn < S) {
      const int nk2 = S - wn;
      const int rowlen = wn - 1;
      const int rlP2 = rowlen | 1;
      const int sub = tid >> 7;          // 0,1: ir halves; 2,3: il halves
      const int typ = sub >> 1, half = sub & 1;
      const int kk2 = tid & 127;
      if (kk2 < nk2 - 1 && rowlen > 0) {
        const int hl = rowlen >> 1;
        const int i0 = half ? hl : 0, i1 = half ? rowlen : hl;
        float* st = &stage[(typ * (nk2 - 1) + kk2) * rlP2];
        const int kr = kk2 + 1;
        if (typ == 0) {
          // ir row k: += SSW[wn-1-i][k+1+i]  (anti-diagonal; coalesced in k)
          const float* pw_ = ssw + (wn - 1) * S + (kr + 1);
#pragma unroll 4
          for (int i = i0; i < i1; ++i) st[i] += pw_[i * (1 - S)];
        } else {
          // il row k: += SSW[1+i][k]  (column; coalesced in k)
          const float* pw_ = ssw + S + kr;
#pragma unroll 4
          for (int i = i0; i < i1; ++i) st[i] += pw_[i * S];
        }
      }
    }
    __syncthreads();   // B3: stage(w+1) complete
  }
}

// Gather score: masked arc scores + positive-sibling scores, count mask.
__global__ __launch_bounds__(256) void score_kernel(
    const float* __restrict__ arc, const float* __restrict__ sib,
    const unsigned char* __restrict__ mask, const int* __restrict__ arcs,
    const int* __restrict__ sibs, int B)
{
  __shared__ bool bytes_sh;
  if (threadIdx.x == 0) {
    int c = 0;
    for (int i = 0; i < S; ++i) c += (mask[i] != 0);
    bytes_sh = (c >= 64);
  }
  __syncthreads();
  const bool bytes = bytes_sh;

  const int total = B * S * S;
  int tid = blockIdx.x * blockDim.x + threadIdx.x;
  float sum = 0.f, cnt = 0.f;
  for (int e = tid; e < total; e += gridDim.x * blockDim.x) {
    int sv = sibs[e];
    if (sv > 0) sum += sib[(size_t)e * S + sv];
    if ((e & (S - 1)) == 0) {           // once per (b,i)
      int bi = e >> 7;
      if (mask_at(mask, bi, bytes)) { sum += arc[(size_t)bi * S + arcs[bi]]; cnt += 1.f; }
    }
  }
  __shared__ float rs[256], rc[256];
  rs[threadIdx.x] = sum; rc[threadIdx.x] = cnt;
  __syncthreads();
  for (int off = 128; off; off >>= 1) {
    if (threadIdx.x < off) {
      rs[threadIdx.x] += rs[threadIdx.x + off];
      rc[threadIdx.x] += rc[threadIdx.x + off];
    }
    __syncthreads();
  }
  if (threadIdx.x == 0) {
    g_partials[blockIdx.x * 2]     = rs[0];
    g_partials[blockIdx.x * 2 + 1] = rc[0];
  }
}

__global__ __launch_bounds__(256) void final_kernel(int B, float* __restrict__ out)
{
  __shared__ float rs[256], rc[256];
  int t = threadIdx.x;
  float v = -g_partials[t * 2];
  float c = g_partials[t * 2 + 1];
  if (t < B) v += g_logZ[t];
  rs[t] = v; rc[t] = c;
  __syncthreads();
  for (int off = 128; off; off >>= 1) {
    if (t < off) { rs[t] += rs[t + off]; rc[t] += rc[t + off]; }
    __syncthreads();
  }
  if (t == 0) out[0] = rs[0] / rc[0];   // (logZ - score) / mask.sum()
}

extern "C" void kernel_launch(void* const* d_in, const int* in_sizes, int n_in,
                              void* d_out, int out_size, void* d_ws, size_t ws_size,
                              hipStream_t stream) {
  const float* s_arc = (const float*)d_in[0];
  const float* s_sib = (const float*)d_in[1];
  const unsigned char* mask = (const unsigned char*)d_in[2];
  const int* arcs = (const int*)d_in[3];
  const int* sibs = (const int*)d_in[4];
  int B = in_sizes[0] / (S * S);
  if (B > MAXB) B = MAXB;

  score_kernel<<<dim3(256), dim3(256), 0, stream>>>(s_arc, s_sib, mask, arcs, sibs, B);
  dp_kernel<<<dim3(B), dim3(NT), 0, stream>>>(s_arc, s_sib, mask);
  final_kernel<<<dim3(1), dim3(256), 0, stream>>>(B, (float*)d_out);
}